// Round 4
// baseline (409.713 us; speedup 1.0000x reference)
//
#include <hip/hip_runtime.h>

typedef unsigned short u16;
typedef unsigned int u32;
typedef __bf16 bf16x8 __attribute__((ext_vector_type(8)));
typedef float f32x4 __attribute__((ext_vector_type(4)));

#define HID 256
#define TEMP_INV 2.0f

__device__ __forceinline__ u16 f2b(float f) {
  union { float f; u32 u; } v; v.f = f;
  u32 u = v.u;
  u += 0x7FFFu + ((u >> 16) & 1u);
  return (u16)(u >> 16);
}
__device__ __forceinline__ float u2f(u32 u) { union { u32 u; float f; } v; v.u = u; return v.f; }

// ---------------- degree count ----------------
__global__ void deg_count_kernel(const int* __restrict__ src, const int* __restrict__ dst,
                                 float* __restrict__ out_deg, float* __restrict__ in_deg, int E) {
  int e = blockIdx.x * blockDim.x + threadIdx.x;
  if (e < E) {
    atomicAdd(&out_deg[src[e]], 1.0f);
    atomicAdd(&in_deg[dst[e]], 1.0f);
  }
}

// ---------------- fused scan: offs, cursor, src_norm, dst_norm ----------------
__global__ __launch_bounds__(256) void scan_fused(const float* __restrict__ in_deg,
                                                  const float* __restrict__ out_deg,
                                                  int* __restrict__ offs, int* __restrict__ cursor,
                                                  float* __restrict__ src_norm,
                                                  float* __restrict__ dst_norm, int N) {
  __shared__ int sums[256];
  int t = threadIdx.x;
  int chunk = N / 256;
  int base = t * chunk;
  int loc = 0;
  for (int i = 0; i < chunk; ++i) loc += (int)in_deg[base + i];
  sums[t] = loc;
  __syncthreads();
  for (int d = 1; d < 256; d <<= 1) {
    int v = (t >= d) ? sums[t - d] : 0;
    __syncthreads();
    sums[t] += v;
    __syncthreads();
  }
  int run = (t == 0) ? 0 : sums[t - 1];
  for (int i = 0; i < chunk; ++i) {
    int n = base + i;
    offs[n] = run;
    cursor[n] = run;
    float id = in_deg[n], od = out_deg[n];
    dst_norm[n] = id > 0.f ? 1.0f / sqrtf(id) : 0.f;
    src_norm[n] = od > 0.f ? 1.0f / sqrtf(od) : 0.f;
    run += (int)id;
  }
  if (t == 255) offs[N] = run;
}

__global__ void csr_fill(const int* __restrict__ src, const int* __restrict__ dst,
                         int* __restrict__ cur, int* __restrict__ csr_src, int E) {
  int e = blockIdx.x * 256 + threadIdx.x;
  if (e < E) {
    int pos = atomicAdd(&cur[dst[e]], 1);
    csr_src[pos] = src[e];
  }
}

// ---------------- conversions / weight packing ----------------
__global__ void cvt_f2b4(const float* __restrict__ in, u16* __restrict__ out, int count4) {
  int i = blockIdx.x * 256 + threadIdx.x;
  if (i < count4) {
    float4 v = ((const float4*)in)[i];
    ((u32*)out)[2 * i] = (u32)f2b(v.x) | ((u32)f2b(v.y) << 16);
    ((u32*)out)[2 * i + 1] = (u32)f2b(v.z) | ((u32)f2b(v.w) << 16);
  }
}

__global__ void build_w1T(const float* __restrict__ W1, const float* __restrict__ Wt1,
                          u16* __restrict__ out) {
  int idx = blockIdx.x * 256 + threadIdx.x;  // 512*512
  int n = idx >> 9, k = idx & 511;
  float v = (n < 256) ? W1[(size_t)k * 256 + n] : Wt1[(size_t)k * 256 + (n - 256)];
  out[idx] = f2b(v);
}

__global__ void build_w2T(const float* __restrict__ W2, const float* __restrict__ Wt2,
                          u16* __restrict__ out) {
  int idx = blockIdx.x * 256 + threadIdx.x;
  int n = idx >> 9, k = idx & 511;
  float v = 0.f;
  if (n < 256) { if (k < 256) v = W2[(size_t)k * 256 + n]; }
  else { if (k >= 256) v = Wt2[(size_t)(k - 256) * 256 + (n - 256)]; }
  out[idx] = f2b(v);
}

__global__ void build_wpT(const float* __restrict__ Wp, u16* __restrict__ out) {
  int idx = blockIdx.x * 256 + threadIdx.x;  // 256*256
  int n = idx >> 8, k = idx & 255;
  out[idx] = f2b(Wp[(size_t)k * 256 + n]);
}

// ---------------- bf16 MFMA GEMM: C[M,Nn] = A[M,K] @ BT[Nn,K]^T ----------------
// MODE 0: bf16 out; MODE 1: f32 out
template <int MODE>
__global__ __launch_bounds__(256) void gemm_bf16(const u16* __restrict__ A,
                                                 const u16* __restrict__ BT,
                                                 void* __restrict__ outp,
                                                 int M, int Nn, int K) {
  __shared__ u16 As[128][40];
  __shared__ u16 Bs[128][40];
  const int t = threadIdx.x;
  const int lane = t & 63, wave = t >> 6;
  const int wm = wave >> 1, wn = wave & 1;
  const size_t m0 = (size_t)blockIdx.x * 128, n0 = (size_t)blockIdx.y * 128;
  const int r16 = lane & 15, kg = lane >> 4;

  f32x4 acc[4][4];
#pragma unroll
  for (int i = 0; i < 4; ++i)
#pragma unroll
    for (int j = 0; j < 4; ++j) acc[i][j] = (f32x4){0.f, 0.f, 0.f, 0.f};

  for (int k0 = 0; k0 < K; k0 += 32) {
#pragma unroll
    for (int i = 0; i < 2; ++i) {
      int ch = t + i * 256;
      int m = ch >> 2, kc = ch & 3;
      *(bf16x8*)&As[m][kc * 8] = *(const bf16x8*)(A + (m0 + m) * (size_t)K + k0 + kc * 8);
      *(bf16x8*)&Bs[m][kc * 8] = *(const bf16x8*)(BT + (n0 + m) * (size_t)K + k0 + kc * 8);
    }
    __syncthreads();
    bf16x8 af[4], bfv[4];
#pragma unroll
    for (int mi = 0; mi < 4; ++mi) af[mi] = *(const bf16x8*)&As[wm * 64 + mi * 16 + r16][kg * 8];
#pragma unroll
    for (int ni = 0; ni < 4; ++ni) bfv[ni] = *(const bf16x8*)&Bs[wn * 64 + ni * 16 + r16][kg * 8];
#pragma unroll
    for (int mi = 0; mi < 4; ++mi)
#pragma unroll
      for (int ni = 0; ni < 4; ++ni)
        acc[mi][ni] = __builtin_amdgcn_mfma_f32_16x16x32_bf16(af[mi], bfv[ni], acc[mi][ni], 0, 0, 0);
    __syncthreads();
  }

#pragma unroll
  for (int mi = 0; mi < 4; ++mi)
#pragma unroll
    for (int rr = 0; rr < 4; ++rr) {
      size_t row = m0 + wm * 64 + mi * 16 + kg * 4 + rr;
#pragma unroll
      for (int ni = 0; ni < 4; ++ni) {
        size_t col = n0 + wn * 64 + ni * 16 + r16;
        if (MODE == 0)
          ((u16*)outp)[row * Nn + col] = f2b(acc[mi][ni][rr]);
        else
          ((float*)outp)[row * Nn + col] = acc[mi][ni][rr];
      }
    }
}

// ---------------- symmetric negsim: upper-triangle blocks only ----------------
// partial[slot][row]: rowsums of exp(2*z_i.z_j) -> partial[bj][bi*128+t];
// colsums (off-diag) -> partial[bi][bj*128+t]. Every cell written once.
__global__ __launch_bounds__(256) void negsim_sym(const u16* __restrict__ zb,
                                                  float* __restrict__ partial, int M) {
  const int bi = blockIdx.x, bj = blockIdx.y;
  if (bi > bj) return;
  __shared__ u16 As[128][40];
  __shared__ u16 Bs[128][40];
  const int t = threadIdx.x;
  const int lane = t & 63, wave = t >> 6;
  const int wm = wave >> 1, wn = wave & 1;
  const size_t m0 = (size_t)bi * 128, n0 = (size_t)bj * 128;
  const int r16 = lane & 15, kg = lane >> 4;
  const int K = 256;

  f32x4 acc[4][4];
#pragma unroll
  for (int i = 0; i < 4; ++i)
#pragma unroll
    for (int j = 0; j < 4; ++j) acc[i][j] = (f32x4){0.f, 0.f, 0.f, 0.f};

  for (int k0 = 0; k0 < K; k0 += 32) {
#pragma unroll
    for (int i = 0; i < 2; ++i) {
      int ch = t + i * 256;
      int m = ch >> 2, kc = ch & 3;
      *(bf16x8*)&As[m][kc * 8] = *(const bf16x8*)(zb + (m0 + m) * (size_t)K + k0 + kc * 8);
      *(bf16x8*)&Bs[m][kc * 8] = *(const bf16x8*)(zb + (n0 + m) * (size_t)K + k0 + kc * 8);
    }
    __syncthreads();
    bf16x8 af[4], bfv[4];
#pragma unroll
    for (int mi = 0; mi < 4; ++mi) af[mi] = *(const bf16x8*)&As[wm * 64 + mi * 16 + r16][kg * 8];
#pragma unroll
    for (int ni = 0; ni < 4; ++ni) bfv[ni] = *(const bf16x8*)&Bs[wn * 64 + ni * 16 + r16][kg * 8];
#pragma unroll
    for (int mi = 0; mi < 4; ++mi)
#pragma unroll
      for (int ni = 0; ni < 4; ++ni)
        acc[mi][ni] = __builtin_amdgcn_mfma_f32_16x16x32_bf16(af[mi], bfv[ni], acc[mi][ni], 0, 0, 0);
    __syncthreads();
  }

  // exp in place
#pragma unroll
  for (int mi = 0; mi < 4; ++mi)
#pragma unroll
    for (int ni = 0; ni < 4; ++ni)
#pragma unroll
      for (int rr = 0; rr < 4; ++rr)
        acc[mi][ni][rr] = __expf(acc[mi][ni][rr] * TEMP_INV);

  float* red = (float*)&As[0][0];  // 512 floats used

  // rowsums: reduce over ni + 16 col-lanes
#pragma unroll
  for (int mi = 0; mi < 4; ++mi)
#pragma unroll
    for (int rr = 0; rr < 4; ++rr) {
      float s = acc[mi][0][rr] + acc[mi][1][rr] + acc[mi][2][rr] + acc[mi][3][rr];
#pragma unroll
      for (int msk = 1; msk < 16; msk <<= 1) s += __shfl_xor(s, msk, 64);
      if (r16 == 0) red[wn * 128 + wm * 64 + mi * 16 + kg * 4 + rr] = s;
    }

  // colsums (only off-diagonal blocks): reduce over mi,rr + kg lanes
  if (bi != bj) {
#pragma unroll
    for (int ni = 0; ni < 4; ++ni) {
      float c = 0.f;
#pragma unroll
      for (int mi = 0; mi < 4; ++mi)
#pragma unroll
        for (int rr = 0; rr < 4; ++rr) c += acc[mi][ni][rr];
      c += __shfl_xor(c, 16, 64);
      c += __shfl_xor(c, 32, 64);
      if (kg == 0) red[256 + wm * 128 + wn * 64 + ni * 16 + r16] = c;
    }
  }
  __syncthreads();
  if (t < 128) {
    partial[(size_t)bj * M + m0 + t] = red[t] + red[128 + t];
    if (bi != bj) partial[(size_t)bi * M + n0 + t] = red[256 + t] + red[384 + t];
  }
}

// ---------------- CSR gather-aggregate, 8B/lane, 2 edge streams ----------------
// LAYER2=false: out = relu(dn*agg+b) -> bf16 512-wide (hb)
// LAYER2=true : out = dn*agg+b -> f32 512-wide (vu) + bf16 of first 256 ch (vb)
template <bool LAYER2>
__global__ __launch_bounds__(256) void agg_csr2(const u16* __restrict__ xw,
                                                const int* __restrict__ csr_src,
                                                const int* __restrict__ offs,
                                                const float* __restrict__ src_norm,
                                                const float* __restrict__ dst_norm,
                                                const float* __restrict__ bias_v,
                                                const float* __restrict__ bias_u,
                                                u16* __restrict__ out_b512,
                                                float* __restrict__ out_f,
                                                u16* __restrict__ out_vb) {
  __shared__ float comb[512];
  const int n = blockIdx.x, t = threadIdx.x;
  const int half = t >> 7, tc = t & 127;
  const int beg = offs[n], end = offs[n + 1];
  float a0 = 0.f, a1 = 0.f, a2 = 0.f, a3 = 0.f;
  for (int i = beg + half; i < end; i += 2) {
    int s = csr_src[i];
    float w = src_norm[s];
    const u32* pp = (const u32*)(xw + (size_t)s * 512) + tc * 2;
    u32 p0 = pp[0], p1 = pp[1];
    a0 += w * u2f(p0 << 16);
    a1 += w * u2f(p0 & 0xFFFF0000u);
    a2 += w * u2f(p1 << 16);
    a3 += w * u2f(p1 & 0xFFFF0000u);
  }
  if (half) {
    comb[tc * 4 + 0] = a0; comb[tc * 4 + 1] = a1;
    comb[tc * 4 + 2] = a2; comb[tc * 4 + 3] = a3;
  }
  __syncthreads();
  if (half == 0) {
    a0 += comb[tc * 4 + 0]; a1 += comb[tc * 4 + 1];
    a2 += comb[tc * 4 + 2]; a3 += comb[tc * 4 + 3];
    float dn = dst_norm[n];
    int c = 4 * tc, cb = c & 255;
    const float* bb = (tc < 64) ? bias_v : bias_u;
    float v0 = dn * a0 + bb[cb + 0];
    float v1 = dn * a1 + bb[cb + 1];
    float v2 = dn * a2 + bb[cb + 2];
    float v3 = dn * a3 + bb[cb + 3];
    if (!LAYER2) {
      v0 = fmaxf(v0, 0.f); v1 = fmaxf(v1, 0.f); v2 = fmaxf(v2, 0.f); v3 = fmaxf(v3, 0.f);
      u32* ob = (u32*)out_b512 + ((size_t)n * 256 + 2 * tc);
      ob[0] = (u32)f2b(v0) | ((u32)f2b(v1) << 16);
      ob[1] = (u32)f2b(v2) | ((u32)f2b(v3) << 16);
    } else {
      *(float4*)(out_f + (size_t)n * 512 + c) = make_float4(v0, v1, v2, v3);
      if (tc < 64) {
        u32* ov = (u32*)out_vb + ((size_t)n * 128 + 2 * tc);
        ov[0] = (u32)f2b(v0) | ((u32)f2b(v1) << 16);
        ov[1] = (u32)f2b(v2) | ((u32)f2b(v3) << 16);
      }
    }
  }
}

// ---------------- l2-normalize one 256-ch row (fp32 in, bf16 out) ----------------
__global__ __launch_bounds__(256) void l2norm_b(const float* __restrict__ in, int ld,
                                                const float* __restrict__ bias,
                                                u16* __restrict__ out) {
  int n = blockIdx.x, c = threadIdx.x;
  float v = in[(size_t)n * ld + c] + (bias ? bias[c] : 0.f);
  float s = v * v;
#pragma unroll
  for (int m = 1; m < 64; m <<= 1) s += __shfl_xor(s, m, 64);
  __shared__ float red[4];
  if ((c & 63) == 0) red[c >> 6] = s;
  __syncthreads();
  float tot = red[0] + red[1] + red[2] + red[3];
  out[(size_t)n * HID + c] = f2b(v / fmaxf(sqrtf(tot), 1e-12f));
}

// ---------------- neg_sim = sum over 64 partials ----------------
__global__ void negsim_reduce(const float* __restrict__ partial, float* __restrict__ neg_sim,
                              int N, int nj) {
  int n = blockIdx.x * 256 + threadIdx.x;
  if (n < N) {
    float s = 0.f;
    for (int j = 0; j < nj; ++j) s += partial[(size_t)j * N + n];
    neg_sim[n] = s;
  }
}

// ---------------- fused edge scores: 16 lanes/edge ----------------
__global__ __launch_bounds__(256) void edge_fused2(const u16* __restrict__ un,
                                                   const u16* __restrict__ q,
                                                   const int* __restrict__ src,
                                                   const int* __restrict__ dst,
                                                   const float* __restrict__ neg_sim,
                                                   float* __restrict__ pos_sum,
                                                   float* __restrict__ neg_sum, int E) {
  int g = threadIdx.x >> 4, sub = threadIdx.x & 15;
  int e = blockIdx.x * 16 + g;
  if (e >= E) return;
  int s = src[e], d = dst[e];
  const u32* pa = (const u32*)(un + (size_t)s * HID) + sub * 8;
  const u32* pb = (const u32*)(q + (size_t)d * HID) + sub * 8;
  float dot = 0.f;
#pragma unroll
  for (int i = 0; i < 8; ++i) {
    u32 a = pa[i], b = pb[i];
    dot += u2f(a << 16) * u2f(b << 16) + u2f(a & 0xFFFF0000u) * u2f(b & 0xFFFF0000u);
  }
#pragma unroll
  for (int m = 1; m < 16; m <<= 1) dot += __shfl_xor(dot, m, 64);
  if (sub == 0) {
    float sim = dot * TEMP_INV;
    atomicAdd(&pos_sum[d], sim);
    atomicAdd(&neg_sum[d], __logf(neg_sim[d] + __expf(sim)));
  }
}

// ---------------- final mean ----------------
__global__ __launch_bounds__(256) void finalize_kernel(const float* __restrict__ pos_sum,
                                                       const float* __restrict__ neg_sum,
                                                       const float* __restrict__ in_deg,
                                                       float* __restrict__ out, int N) {
  float acc = 0.f;
  for (int n = threadIdx.x; n < N; n += 256) {
    float d = in_deg[n];
    if (d > 0.f) acc += (neg_sum[n] - pos_sum[n]) / fmaxf(d, 1.0f);
  }
#pragma unroll
  for (int m = 1; m < 64; m <<= 1) acc += __shfl_xor(acc, m, 64);
  __shared__ float red[4];
  if ((threadIdx.x & 63) == 0) red[threadIdx.x >> 6] = acc;
  __syncthreads();
  if (threadIdx.x == 0) out[0] = (red[0] + red[1] + red[2] + red[3]) / (float)N;
}

extern "C" void kernel_launch(void* const* d_in, const int* in_sizes, int n_in,
                              void* d_out, int out_size, void* d_ws, size_t ws_size,
                              hipStream_t stream) {
  const float* feat = (const float*)d_in[0];
  const int* src = (const int*)d_in[1];
  const int* dst = (const int*)d_in[2];
  const float* W1 = (const float*)d_in[3];
  const float* b1 = (const float*)d_in[4];
  const float* W2 = (const float*)d_in[5];
  const float* b2 = (const float*)d_in[6];
  const float* Wt1 = (const float*)d_in[7];
  const float* bt1 = (const float*)d_in[8];
  const float* Wt2 = (const float*)d_in[9];
  const float* bt2 = (const float*)d_in[10];
  const float* Wp = (const float*)d_in[11];
  const float* bp = (const float*)d_in[12];

  const int N = in_sizes[0] / 512;  // 8192
  const int E = in_sizes[1];        // 262144
  const int NJB = N / 128;          // 64 j-blocks for negsim

  char* w = (char*)d_ws;
  size_t off = 0;
  auto alloc = [&](size_t bytes) -> void* {
    void* p = w + off;
    off = (off + bytes + 255) & ~(size_t)255;
    return p;
  };

  float* out_deg = (float*)alloc((size_t)N * 4);
  float* in_deg = (float*)alloc((size_t)N * 4);
  float* src_nrm = (float*)alloc((size_t)N * 4);
  float* dst_nrm = (float*)alloc((size_t)N * 4);
  float* neg_sim = (float*)alloc((size_t)N * 4);
  float* pos_sum = (float*)alloc((size_t)N * 4);
  float* neg_sum = (float*)alloc((size_t)N * 4);
  int* offs = (int*)alloc((size_t)(N + 1) * 4);
  int* cursor = (int*)alloc((size_t)N * 4);
  int* csr_src = (int*)alloc((size_t)E * 4);
  u16* w1T = (u16*)alloc(512 * 512 * 2);
  u16* w2T = (u16*)alloc(512 * 512 * 2);
  u16* wpT = (u16*)alloc(256 * 256 * 2);
  u16* featb = (u16*)alloc((size_t)N * 512 * 2);  // later reused: q_pre (f32 N*256)
  u16* XWb = (u16*)alloc((size_t)N * 512 * 2);    // later: zb | unb
  u16* hb = (u16*)alloc((size_t)N * 512 * 2);     // later: vb | qb
  float* vu = (float*)alloc((size_t)N * 512 * 4);
  float* partial = (float*)alloc((size_t)NJB * N * 4);

  float* q_pre = (float*)featb;
  u16* zb = XWb;
  u16* unb = XWb + (size_t)N * 256;
  u16* vb = hb;
  u16* qb = hb + (size_t)N * 256;

  dim3 b256(256);

  // degrees, norms, CSR
  hipMemsetAsync(out_deg, 0, 2 * (size_t)N * 4, stream);
  deg_count_kernel<<<(E + 255) / 256, b256, 0, stream>>>(src, dst, out_deg, in_deg, E);
  scan_fused<<<1, b256, 0, stream>>>(in_deg, out_deg, offs, cursor, src_nrm, dst_nrm, N);
  csr_fill<<<(E + 255) / 256, b256, 0, stream>>>(src, dst, cursor, csr_src, E);

  // pack inputs/weights to bf16
  cvt_f2b4<<<(N * 128 + 255) / 256, b256, 0, stream>>>(feat, featb, N * 128);
  build_w1T<<<(512 * 512) / 256, b256, 0, stream>>>(W1, Wt1, w1T);
  build_w2T<<<(512 * 512) / 256, b256, 0, stream>>>(W2, Wt2, w2T);
  build_wpT<<<(256 * 256) / 256, b256, 0, stream>>>(Wp, wpT);

  // layer 1 (online+target fused): XW = feat @ [W1|Wt1]; h = relu(dn*agg + b)
  gemm_bf16<0><<<dim3(N / 128, 4), b256, 0, stream>>>(featb, w1T, XWb, N, 512, 512);
  agg_csr2<false><<<N, b256, 0, stream>>>(XWb, csr_src, offs, src_nrm, dst_nrm, b1, bt1,
                                          hb, nullptr, nullptr);

  // layer 2: XW2 = h @ blockdiag(W2,Wt2); vu = dn*agg + b (+ vb bf16)
  gemm_bf16<0><<<dim3(N / 128, 4), b256, 0, stream>>>(hb, w2T, XWb, N, 512, 512);
  agg_csr2<true><<<N, b256, 0, stream>>>(XWb, csr_src, offs, src_nrm, dst_nrm, b2, bt2,
                                         nullptr, vu, vb);

  // z, un, projector q
  l2norm_b<<<N, b256, 0, stream>>>(vu, 512, nullptr, zb);
  l2norm_b<<<N, b256, 0, stream>>>(vu + 256, 512, nullptr, unb);
  gemm_bf16<1><<<dim3(N / 128, 2), b256, 0, stream>>>(vb, wpT, q_pre, N, 256, 256);
  l2norm_b<<<N, b256, 0, stream>>>(q_pre, 256, bp, qb);

  // neg_sim = rowsum exp(2 * z z^T), symmetric upper-triangle blocks
  negsim_sym<<<dim3(NJB, NJB), b256, 0, stream>>>(zb, partial, N);
  negsim_reduce<<<(N + 255) / 256, b256, 0, stream>>>(partial, neg_sim, N, NJB);

  // edge scores + segment sums
  hipMemsetAsync(pos_sum, 0, 2 * (size_t)N * 4, stream);
  edge_fused2<<<(E + 15) / 16, b256, 0, stream>>>(unb, qb, src, dst, neg_sim, pos_sum, neg_sum, E);

  finalize_kernel<<<1, b256, 0, stream>>>(pos_sum, neg_sum, in_deg, (float*)d_out, N);
}

// Round 5
// 350.251 us; speedup vs baseline: 1.1698x; 1.1698x over previous
//
#include <hip/hip_runtime.h>

typedef unsigned short u16;
typedef unsigned int u32;
typedef __bf16 bf16x8 __attribute__((ext_vector_type(8)));
typedef float f32x4 __attribute__((ext_vector_type(4)));

#define HID 256
#define TEMP_INV 2.0f

__device__ __forceinline__ u16 f2b(float f) {
  union { float f; u32 u; } v; v.f = f;
  u32 u = v.u;
  u += 0x7FFFu + ((u >> 16) & 1u);
  return (u16)(u >> 16);
}
__device__ __forceinline__ float u2f(u32 u) { union { u32 u; float f; } v; v.u = u; return v.f; }

// ---------------- degree count ----------------
__global__ void deg_count_kernel(const int* __restrict__ src, const int* __restrict__ dst,
                                 float* __restrict__ out_deg, float* __restrict__ in_deg, int E) {
  int e = blockIdx.x * blockDim.x + threadIdx.x;
  if (e < E) {
    atomicAdd(&out_deg[src[e]], 1.0f);
    atomicAdd(&in_deg[dst[e]], 1.0f);
  }
}

// ---------------- fused scan (LDS-staged, coalesced): offs, cursor, norms ----------------
__global__ __launch_bounds__(256) void scan_fused(const float* __restrict__ in_deg,
                                                  const float* __restrict__ out_deg,
                                                  int* __restrict__ offs, int* __restrict__ cursor,
                                                  float* __restrict__ src_norm,
                                                  float* __restrict__ dst_norm, int N) {
  __shared__ float sdeg[8192];
  __shared__ int sums[256];
  int t = threadIdx.x;
  for (int i = t; i < N; i += 256) sdeg[i] = in_deg[i];
  __syncthreads();
  const int chunk = N / 256;
  int base = t * chunk;
  int loc = 0;
  for (int i = 0; i < chunk; ++i) loc += (int)sdeg[base + i];
  sums[t] = loc;
  __syncthreads();
  for (int d = 1; d < 256; d <<= 1) {
    int v = (t >= d) ? sums[t - d] : 0;
    __syncthreads();
    sums[t] += v;
    __syncthreads();
  }
  int run = (t == 0) ? 0 : sums[t - 1];
  for (int i = 0; i < chunk; ++i) {
    int n = base + i;
    offs[n] = run;
    cursor[n] = run;
    run += (int)sdeg[n];
  }
  if (t == 255) offs[N] = run;
  for (int i = t; i < N; i += 256) {
    float id = sdeg[i], od = out_deg[i];
    dst_norm[i] = id > 0.f ? 1.0f / sqrtf(id) : 0.f;
    src_norm[i] = od > 0.f ? 1.0f / sqrtf(od) : 0.f;
  }
}

__global__ void csr_fill(const int* __restrict__ src, const int* __restrict__ dst,
                         int* __restrict__ cur, int* __restrict__ csr_src, int E) {
  int e = blockIdx.x * 256 + threadIdx.x;
  if (e < E) {
    int pos = atomicAdd(&cur[dst[e]], 1);
    csr_src[pos] = src[e];
  }
}

// ---------------- merged packing: feat->bf16, w1T, w2T, wpT ----------------
__global__ void pack_all(const float* __restrict__ feat,
                         const float* __restrict__ W1, const float* __restrict__ Wt1,
                         const float* __restrict__ W2, const float* __restrict__ Wt2,
                         const float* __restrict__ Wp,
                         u16* __restrict__ featb, u16* __restrict__ w1T,
                         u16* __restrict__ w2T, u16* __restrict__ wpT, int N) {
  const int CVT = N * 128 / 256;  // feat float4 blocks
  int bid = blockIdx.x, t = threadIdx.x;
  if (bid < CVT) {
    int i = bid * 256 + t;
    float4 v = ((const float4*)feat)[i];
    ((u32*)featb)[2 * i] = (u32)f2b(v.x) | ((u32)f2b(v.y) << 16);
    ((u32*)featb)[2 * i + 1] = (u32)f2b(v.z) | ((u32)f2b(v.w) << 16);
  } else if (bid < CVT + 1024) {
    int idx = (bid - CVT) * 256 + t;
    int n = idx >> 9, k = idx & 511;
    float v = (n < 256) ? W1[(size_t)k * 256 + n] : Wt1[(size_t)k * 256 + (n - 256)];
    w1T[idx] = f2b(v);
  } else if (bid < CVT + 2048) {
    int idx = (bid - CVT - 1024) * 256 + t;
    int n = idx >> 9, k = idx & 511;
    float v = 0.f;
    if (n < 256) { if (k < 256) v = W2[(size_t)k * 256 + n]; }
    else { if (k >= 256) v = Wt2[(size_t)(k - 256) * 256 + (n - 256)]; }
    w2T[idx] = f2b(v);
  } else {
    int idx = (bid - CVT - 2048) * 256 + t;
    int n = idx >> 8, k = idx & 255;
    wpT[idx] = f2b(Wp[(size_t)k * 256 + n]);
  }
}

// ---------------- bf16 MFMA GEMM: C[M,Nn] = A[M,K] @ BT[Nn,K]^T ----------------
template <int MODE>  // 0: bf16 out; 1: f32 out
__global__ __launch_bounds__(256) void gemm_bf16(const u16* __restrict__ A,
                                                 const u16* __restrict__ BT,
                                                 void* __restrict__ outp,
                                                 int M, int Nn, int K) {
  __shared__ u16 As[128][40];
  __shared__ u16 Bs[128][40];
  const int t = threadIdx.x;
  const int lane = t & 63, wave = t >> 6;
  const int wm = wave >> 1, wn = wave & 1;
  const size_t m0 = (size_t)blockIdx.x * 128, n0 = (size_t)blockIdx.y * 128;
  const int r16 = lane & 15, kg = lane >> 4;

  f32x4 acc[4][4];
#pragma unroll
  for (int i = 0; i < 4; ++i)
#pragma unroll
    for (int j = 0; j < 4; ++j) acc[i][j] = (f32x4){0.f, 0.f, 0.f, 0.f};

  for (int k0 = 0; k0 < K; k0 += 32) {
#pragma unroll
    for (int i = 0; i < 2; ++i) {
      int ch = t + i * 256;
      int m = ch >> 2, kc = ch & 3;
      *(bf16x8*)&As[m][kc * 8] = *(const bf16x8*)(A + (m0 + m) * (size_t)K + k0 + kc * 8);
      *(bf16x8*)&Bs[m][kc * 8] = *(const bf16x8*)(BT + (n0 + m) * (size_t)K + k0 + kc * 8);
    }
    __syncthreads();
    bf16x8 af[4], bfv[4];
#pragma unroll
    for (int mi = 0; mi < 4; ++mi) af[mi] = *(const bf16x8*)&As[wm * 64 + mi * 16 + r16][kg * 8];
#pragma unroll
    for (int ni = 0; ni < 4; ++ni) bfv[ni] = *(const bf16x8*)&Bs[wn * 64 + ni * 16 + r16][kg * 8];
#pragma unroll
    for (int mi = 0; mi < 4; ++mi)
#pragma unroll
      for (int ni = 0; ni < 4; ++ni)
        acc[mi][ni] = __builtin_amdgcn_mfma_f32_16x16x32_bf16(af[mi], bfv[ni], acc[mi][ni], 0, 0, 0);
    __syncthreads();
  }

#pragma unroll
  for (int mi = 0; mi < 4; ++mi)
#pragma unroll
    for (int rr = 0; rr < 4; ++rr) {
      size_t row = m0 + wm * 64 + mi * 16 + kg * 4 + rr;
#pragma unroll
      for (int ni = 0; ni < 4; ++ni) {
        size_t col = n0 + wn * 64 + ni * 16 + r16;
        if (MODE == 0)
          ((u16*)outp)[row * Nn + col] = f2b(acc[mi][ni][rr]);
        else
          ((float*)outp)[row * Nn + col] = acc[mi][ni][rr];
      }
    }
}

// ---------------- negsim: A-in-registers, 4 j-tiles/block, upper triangle ----------------
// Block (bi, jc) handles j-tiles bj = bi+4*jc .. min(bi+4*jc+3, NJB-1).
// Rowsums accumulate in-register across tiles -> partial[NJB+jc][rows bi].
// Colsums (bj != bi) -> partial[bi][cols bj]. Unwritten cells stay 0 (memset).
__global__ __launch_bounds__(256, 2) void negsim_strip(const u16* __restrict__ zb,
                                                       float* __restrict__ partial,
                                                       int M, int NJB) {
  // map linear block -> (bi, jc)
  int bid = blockIdx.x;
  int bi = 0, cum = 0;
  for (;;) {
    int nch = (NJB - bi + 3) >> 2;
    if (bid < cum + nch) break;
    cum += nch;
    ++bi;
  }
  const int jc = bid - cum;
  const int bj0 = bi + jc * 4;
  const int ntiles = min(4, NJB - bj0);

  __shared__ u16 Bs[128][40];
  __shared__ float red[512];
  const int t = threadIdx.x;
  const int lane = t & 63, wave = t >> 6;
  const int wm = wave >> 1, wn = wave & 1;
  const int r16 = lane & 15, kg = lane >> 4;
  const size_t m0 = (size_t)bi * 128;

  // preload A fragments for full K=256 into registers (32 x bf16x8)
  bf16x8 af[4][8];
#pragma unroll
  for (int mi = 0; mi < 4; ++mi) {
    const u16* arow = zb + (m0 + wm * 64 + mi * 16 + r16) * (size_t)HID + kg * 8;
#pragma unroll
    for (int k0 = 0; k0 < 8; ++k0) af[mi][k0] = *(const bf16x8*)(arow + k0 * 32);
  }

  float rs[4][4];
#pragma unroll
  for (int mi = 0; mi < 4; ++mi)
#pragma unroll
    for (int rr = 0; rr < 4; ++rr) rs[mi][rr] = 0.f;

  for (int tt = 0; tt < ntiles; ++tt) {
    const int bj = bj0 + tt;
    const size_t n0 = (size_t)bj * 128;
    f32x4 acc[4][4];
#pragma unroll
    for (int i = 0; i < 4; ++i)
#pragma unroll
      for (int j = 0; j < 4; ++j) acc[i][j] = (f32x4){0.f, 0.f, 0.f, 0.f};

#pragma unroll
    for (int k0 = 0; k0 < 8; ++k0) {
      __syncthreads();
#pragma unroll
      for (int i = 0; i < 2; ++i) {
        int ch = t + i * 256;
        int m = ch >> 2, kc = ch & 3;
        *(bf16x8*)&Bs[m][kc * 8] = *(const bf16x8*)(zb + (n0 + m) * (size_t)HID + k0 * 32 + kc * 8);
      }
      __syncthreads();
      bf16x8 bfv[4];
#pragma unroll
      for (int ni = 0; ni < 4; ++ni) bfv[ni] = *(const bf16x8*)&Bs[wn * 64 + ni * 16 + r16][kg * 8];
#pragma unroll
      for (int mi = 0; mi < 4; ++mi)
#pragma unroll
        for (int ni = 0; ni < 4; ++ni)
          acc[mi][ni] = __builtin_amdgcn_mfma_f32_16x16x32_bf16(af[mi][k0], bfv[ni], acc[mi][ni], 0, 0, 0);
    }

    // exp in place
#pragma unroll
    for (int mi = 0; mi < 4; ++mi)
#pragma unroll
      for (int ni = 0; ni < 4; ++ni)
#pragma unroll
        for (int rr = 0; rr < 4; ++rr)
          acc[mi][ni][rr] = __expf(acc[mi][ni][rr] * TEMP_INV);

    // accumulate rowsums in-register
#pragma unroll
    for (int mi = 0; mi < 4; ++mi)
#pragma unroll
      for (int rr = 0; rr < 4; ++rr)
        rs[mi][rr] += acc[mi][0][rr] + acc[mi][1][rr] + acc[mi][2][rr] + acc[mi][3][rr];

    // colsums for off-diagonal tiles
    if (bj != bi) {
#pragma unroll
      for (int ni = 0; ni < 4; ++ni) {
        float c = 0.f;
#pragma unroll
        for (int mi = 0; mi < 4; ++mi)
#pragma unroll
          for (int rr = 0; rr < 4; ++rr) c += acc[mi][ni][rr];
        c += __shfl_xor(c, 16, 64);
        c += __shfl_xor(c, 32, 64);
        if (kg == 0) red[wm * 256 + wn * 64 + ni * 16 + r16] = c;
      }
      __syncthreads();
      if (t < 128) partial[(size_t)bi * M + n0 + t] = red[t] + red[256 + t];
    }
  }

  // rowsum epilogue: reduce over 16 col-lanes, combine wn halves via LDS
  __syncthreads();
#pragma unroll
  for (int mi = 0; mi < 4; ++mi)
#pragma unroll
    for (int rr = 0; rr < 4; ++rr) {
      float s = rs[mi][rr];
      s += __shfl_xor(s, 1, 64);
      s += __shfl_xor(s, 2, 64);
      s += __shfl_xor(s, 4, 64);
      s += __shfl_xor(s, 8, 64);
      if (r16 == 0) red[wn * 128 + wm * 64 + mi * 16 + kg * 4 + rr] = s;
    }
  __syncthreads();
  if (t < 128) partial[(size_t)(NJB + jc) * M + m0 + t] = red[t] + red[128 + t];
}

// ---------------- CSR gather-aggregate (round-3 proven shape + fused vb) ----------------
template <bool LAYER2>
__global__ __launch_bounds__(256) void agg_csr(const u16* __restrict__ xw,
                                               const int* __restrict__ csr_src,
                                               const int* __restrict__ offs,
                                               const float* __restrict__ src_norm,
                                               const float* __restrict__ dst_norm,
                                               const float* __restrict__ bias_v,
                                               const float* __restrict__ bias_u,
                                               u16* __restrict__ out_b512,
                                               float* __restrict__ out_f,
                                               u16* __restrict__ out_vb) {
  const int n = blockIdx.x, t = threadIdx.x;
  const int beg = offs[n], end = offs[n + 1];
  float a0 = 0.f, a1 = 0.f;
  int i = beg;
  for (; i + 2 <= end; i += 2) {
    int s0 = csr_src[i], s1 = csr_src[i + 1];
    float w0 = src_norm[s0], w1 = src_norm[s1];
    u32 p0 = *(const u32*)(xw + (size_t)s0 * 512 + t * 2);
    u32 p1 = *(const u32*)(xw + (size_t)s1 * 512 + t * 2);
    a0 += w0 * u2f(p0 << 16);
    a1 += w0 * u2f(p0 & 0xFFFF0000u);
    a0 += w1 * u2f(p1 << 16);
    a1 += w1 * u2f(p1 & 0xFFFF0000u);
  }
  if (i < end) {
    int s0 = csr_src[i];
    float w0 = src_norm[s0];
    u32 p0 = *(const u32*)(xw + (size_t)s0 * 512 + t * 2);
    a0 += w0 * u2f(p0 << 16);
    a1 += w0 * u2f(p0 & 0xFFFF0000u);
  }
  float dn = dst_norm[n];
  const float* bb = (t < 128) ? bias_v : bias_u;
  int cc = (2 * t) & 255;
  float v0 = dn * a0 + bb[cc], v1 = dn * a1 + bb[cc + 1];
  if (!LAYER2) {
    v0 = fmaxf(v0, 0.f);
    v1 = fmaxf(v1, 0.f);
    ((u32*)out_b512)[(size_t)n * 256 + t] = (u32)f2b(v0) | ((u32)f2b(v1) << 16);
  } else {
    *(float2*)(out_f + (size_t)n * 512 + 2 * t) = make_float2(v0, v1);
    if (t < 128)
      ((u32*)out_vb)[(size_t)n * 128 + t] = (u32)f2b(v0) | ((u32)f2b(v1) << 16);
  }
}

// ---------------- merged l2norm for z (cols 0..255) and un (cols 256..511) ----------------
__global__ __launch_bounds__(256) void l2norm_zu(const float* __restrict__ vu,
                                                 u16* __restrict__ zb, u16* __restrict__ unb,
                                                 int N) {
  int b = blockIdx.x;
  int isu = b >= N;
  int n = isu ? b - N : b;
  int c = threadIdx.x;
  const float* in = vu + (size_t)n * 512 + (isu ? 256 : 0);
  u16* out = (isu ? unb : zb) + (size_t)n * HID;
  float v = in[c];
  float s = v * v;
#pragma unroll
  for (int m = 1; m < 64; m <<= 1) s += __shfl_xor(s, m, 64);
  __shared__ float red[4];
  if ((c & 63) == 0) red[c >> 6] = s;
  __syncthreads();
  float tot = red[0] + red[1] + red[2] + red[3];
  out[c] = f2b(v / fmaxf(sqrtf(tot), 1e-12f));
}

__global__ __launch_bounds__(256) void l2norm_b(const float* __restrict__ in, int ld,
                                                const float* __restrict__ bias,
                                                u16* __restrict__ out) {
  int n = blockIdx.x, c = threadIdx.x;
  float v = in[(size_t)n * ld + c] + (bias ? bias[c] : 0.f);
  float s = v * v;
#pragma unroll
  for (int m = 1; m < 64; m <<= 1) s += __shfl_xor(s, m, 64);
  __shared__ float red[4];
  if ((c & 63) == 0) red[c >> 6] = s;
  __syncthreads();
  float tot = red[0] + red[1] + red[2] + red[3];
  out[(size_t)n * HID + c] = f2b(v / fmaxf(sqrtf(tot), 1e-12f));
}

// ---------------- neg_sim = sum over partial slots ----------------
__global__ void negsim_reduce(const float* __restrict__ partial, float* __restrict__ neg_sim,
                              int N, int nj) {
  int n = blockIdx.x * 256 + threadIdx.x;
  if (n < N) {
    float s = 0.f;
    for (int j = 0; j < nj; ++j) s += partial[(size_t)j * N + n];
    neg_sim[n] = s;
  }
}

// ---------------- fused edge scores: 16 lanes/edge, uint4 loads ----------------
__global__ __launch_bounds__(256) void edge_fused2(const u16* __restrict__ un,
                                                   const u16* __restrict__ q,
                                                   const int* __restrict__ src,
                                                   const int* __restrict__ dst,
                                                   const float* __restrict__ neg_sim,
                                                   float* __restrict__ pos_sum,
                                                   float* __restrict__ neg_sum, int E) {
  int g = threadIdx.x >> 4, sub = threadIdx.x & 15;
  int e = blockIdx.x * 16 + g;
  if (e >= E) return;
  int s = src[e], d = dst[e];
  const uint4* pa = (const uint4*)(un + (size_t)s * HID) + sub * 2;
  const uint4* pb = (const uint4*)(q + (size_t)d * HID) + sub * 2;
  uint4 A0 = pa[0], A1 = pa[1], B0 = pb[0], B1 = pb[1];
  float dot = 0.f;
  u32 aw[8] = {A0.x, A0.y, A0.z, A0.w, A1.x, A1.y, A1.z, A1.w};
  u32 bw[8] = {B0.x, B0.y, B0.z, B0.w, B1.x, B1.y, B1.z, B1.w};
#pragma unroll
  for (int i = 0; i < 8; ++i) {
    dot += u2f(aw[i] << 16) * u2f(bw[i] << 16) +
           u2f(aw[i] & 0xFFFF0000u) * u2f(bw[i] & 0xFFFF0000u);
  }
#pragma unroll
  for (int m = 1; m < 16; m <<= 1) dot += __shfl_xor(dot, m, 64);
  if (sub == 0) {
    float sim = dot * TEMP_INV;
    atomicAdd(&pos_sum[d], sim);
    atomicAdd(&neg_sum[d], __logf(neg_sim[d] + __expf(sim)));
  }
}

// ---------------- final mean ----------------
__global__ __launch_bounds__(256) void finalize_kernel(const float* __restrict__ pos_sum,
                                                       const float* __restrict__ neg_sum,
                                                       const float* __restrict__ in_deg,
                                                       float* __restrict__ out, int N) {
  float acc = 0.f;
  for (int n = threadIdx.x; n < N; n += 256) {
    float d = in_deg[n];
    if (d > 0.f) acc += (neg_sum[n] - pos_sum[n]) / fmaxf(d, 1.0f);
  }
#pragma unroll
  for (int m = 1; m < 64; m <<= 1) acc += __shfl_xor(acc, m, 64);
  __shared__ float red[4];
  if ((threadIdx.x & 63) == 0) red[threadIdx.x >> 6] = acc;
  __syncthreads();
  if (threadIdx.x == 0) out[0] = (red[0] + red[1] + red[2] + red[3]) / (float)N;
}

extern "C" void kernel_launch(void* const* d_in, const int* in_sizes, int n_in,
                              void* d_out, int out_size, void* d_ws, size_t ws_size,
                              hipStream_t stream) {
  const float* feat = (const float*)d_in[0];
  const int* src = (const int*)d_in[1];
  const int* dst = (const int*)d_in[2];
  const float* W1 = (const float*)d_in[3];
  const float* b1 = (const float*)d_in[4];
  const float* W2 = (const float*)d_in[5];
  const float* b2 = (const float*)d_in[6];
  const float* Wt1 = (const float*)d_in[7];
  const float* bt1 = (const float*)d_in[8];
  const float* Wt2 = (const float*)d_in[9];
  const float* bt2 = (const float*)d_in[10];
  const float* Wp = (const float*)d_in[11];
  const float* bp = (const float*)d_in[12];

  const int N = in_sizes[0] / 512;  // 8192
  const int E = in_sizes[1];        // 262144
  const int NJB = N / 128;          // 64
  const int NSLOT = NJB + 16;       // col slots + row-chunk slots

  // total strip blocks = sum_{bi} ceil((NJB-bi)/4)
  int nstrip = 0;
  for (int bi = 0; bi < NJB; ++bi) nstrip += (NJB - bi + 3) >> 2;

  char* w = (char*)d_ws;
  size_t off = 0;
  auto alloc = [&](size_t bytes) -> void* {
    void* p = w + off;
    off = (off + bytes + 255) & ~(size_t)255;
    return p;
  };

  float* out_deg = (float*)alloc((size_t)N * 4);
  float* in_deg = (float*)alloc((size_t)N * 4);
  float* src_nrm = (float*)alloc((size_t)N * 4);
  float* dst_nrm = (float*)alloc((size_t)N * 4);
  float* neg_sim = (float*)alloc((size_t)N * 4);
  float* pos_sum = (float*)alloc((size_t)N * 4);
  float* neg_sum = (float*)alloc((size_t)N * 4);
  int* offs = (int*)alloc((size_t)(N + 1) * 4);
  int* cursor = (int*)alloc((size_t)N * 4);
  int* csr_src = (int*)alloc((size_t)E * 4);
  u16* w1T = (u16*)alloc(512 * 512 * 2);
  u16* w2T = (u16*)alloc(512 * 512 * 2);
  u16* wpT = (u16*)alloc(256 * 256 * 2);
  u16* featb = (u16*)alloc((size_t)N * 512 * 2);  // reused later: q_pre (f32 N*256)
  u16* XWb = (u16*)alloc((size_t)N * 512 * 2);    // later: zb | unb
  u16* hb = (u16*)alloc((size_t)N * 512 * 2);     // later: vb | qb
  float* vu = (float*)alloc((size_t)N * 512 * 4);
  float* partial = (float*)alloc((size_t)NSLOT * N * 4);

  float* q_pre = (float*)featb;
  u16* zb = XWb;
  u16* unb = XWb + (size_t)N * 256;
  u16* vb = hb;
  u16* qb = hb + (size_t)N * 256;

  dim3 b256(256);

  // degrees, norms, CSR
  hipMemsetAsync(out_deg, 0, 2 * (size_t)N * 4, stream);
  deg_count_kernel<<<(E + 255) / 256, b256, 0, stream>>>(src, dst, out_deg, in_deg, E);
  scan_fused<<<1, b256, 0, stream>>>(in_deg, out_deg, offs, cursor, src_nrm, dst_nrm, N);
  csr_fill<<<(E + 255) / 256, b256, 0, stream>>>(src, dst, cursor, csr_src, E);

  // pack inputs/weights to bf16 (merged)
  pack_all<<<N * 128 / 256 + 2048 + 256, b256, 0, stream>>>(feat, W1, Wt1, W2, Wt2, Wp,
                                                            featb, w1T, w2T, wpT, N);

  // layer 1 (online+target fused)
  gemm_bf16<0><<<dim3(N / 128, 4), b256, 0, stream>>>(featb, w1T, XWb, N, 512, 512);
  agg_csr<false><<<N, b256, 0, stream>>>(XWb, csr_src, offs, src_nrm, dst_nrm, b1, bt1,
                                         hb, nullptr, nullptr);

  // layer 2
  gemm_bf16<0><<<dim3(N / 128, 4), b256, 0, stream>>>(hb, w2T, XWb, N, 512, 512);
  agg_csr<true><<<N, b256, 0, stream>>>(XWb, csr_src, offs, src_nrm, dst_nrm, b2, bt2,
                                        nullptr, vu, vb);

  // z, un (merged), projector q
  l2norm_zu<<<2 * N, b256, 0, stream>>>(vu, zb, unb, N);
  gemm_bf16<1><<<dim3(N / 128, 2), b256, 0, stream>>>(vb, wpT, q_pre, N, 256, 256);
  l2norm_b<<<N, b256, 0, stream>>>(q_pre, 256, bp, qb);

  // neg_sim: A-in-registers strip kernel over upper triangle
  hipMemsetAsync(partial, 0, (size_t)NSLOT * N * 4, stream);
  negsim_strip<<<nstrip, b256, 0, stream>>>(zb, partial, N, NJB);
  negsim_reduce<<<(N + 255) / 256, b256, 0, stream>>>(partial, neg_sim, N, NSLOT);

  // edge scores + segment sums
  hipMemsetAsync(pos_sum, 0, 2 * (size_t)N * 4, stream);
  edge_fused2<<<(E + 15) / 16, b256, 0, stream>>>(unb, qb, src, dst, neg_sim, pos_sum, neg_sum, E);

  finalize_kernel<<<1, b256, 0, stream>>>(pos_sum, neg_sum, in_deg, (float*)d_out, N);
}

// Round 7
// 324.571 us; speedup vs baseline: 1.2623x; 1.0791x over previous
//
#include <hip/hip_runtime.h>

typedef unsigned short u16;
typedef unsigned int u32;
typedef __bf16 bf16x8 __attribute__((ext_vector_type(8)));
typedef float f32x4 __attribute__((ext_vector_type(4)));

#define HID 256
#define TEMP_INV 2.0f

__device__ __forceinline__ u16 f2b(float f) {
  union { float f; u32 u; } v; v.f = f;
  u32 u = v.u;
  u += 0x7FFFu + ((u >> 16) & 1u);
  return (u16)(u >> 16);
}
__device__ __forceinline__ float u2f(u32 u) { union { u32 u; float f; } v; v.u = u; return v.f; }

typedef __attribute__((address_space(1))) const unsigned int ga_u32;
typedef __attribute__((address_space(3))) unsigned int ls_u32;
__device__ __forceinline__ void gload_lds16(const void* g, void* l) {
  __builtin_amdgcn_global_load_lds((ga_u32*)g, (ls_u32*)l, 16, 0, 0);
}

// ---------------- degree count ----------------
__global__ void deg_count_kernel(const int* __restrict__ src, const int* __restrict__ dst,
                                 float* __restrict__ out_deg, float* __restrict__ in_deg, int E) {
  int e = blockIdx.x * blockDim.x + threadIdx.x;
  if (e < E) {
    atomicAdd(&out_deg[src[e]], 1.0f);
    atomicAdd(&in_deg[dst[e]], 1.0f);
  }
}

// ---------------- fused scan (LDS-staged): offs, cursor, norms ----------------
__global__ __launch_bounds__(256) void scan_fused(const float* __restrict__ in_deg,
                                                  const float* __restrict__ out_deg,
                                                  int* __restrict__ offs, int* __restrict__ cursor,
                                                  float* __restrict__ src_norm,
                                                  float* __restrict__ dst_norm, int N) {
  __shared__ float sdeg[8192];
  __shared__ int sums[256];
  int t = threadIdx.x;
  for (int i = t; i < N; i += 256) sdeg[i] = in_deg[i];
  __syncthreads();
  const int chunk = N / 256;
  int base = t * chunk;
  int loc = 0;
  for (int i = 0; i < chunk; ++i) loc += (int)sdeg[base + i];
  sums[t] = loc;
  __syncthreads();
  for (int d = 1; d < 256; d <<= 1) {
    int v = (t >= d) ? sums[t - d] : 0;
    __syncthreads();
    sums[t] += v;
    __syncthreads();
  }
  int run = (t == 0) ? 0 : sums[t - 1];
  for (int i = 0; i < chunk; ++i) {
    int n = base + i;
    offs[n] = run;
    cursor[n] = run;
    run += (int)sdeg[n];
  }
  if (t == 255) offs[N] = run;
  for (int i = t; i < N; i += 256) {
    float id = sdeg[i], od = out_deg[i];
    dst_norm[i] = id > 0.f ? 1.0f / sqrtf(id) : 0.f;
    src_norm[i] = od > 0.f ? 1.0f / sqrtf(od) : 0.f;
  }
}

__global__ void csr_fill(const int* __restrict__ src, const int* __restrict__ dst,
                         int* __restrict__ cur, int* __restrict__ csr_src, int E) {
  int e = blockIdx.x * 256 + threadIdx.x;
  if (e < E) {
    int pos = atomicAdd(&cur[dst[e]], 1);
    csr_src[pos] = src[e];
  }
}

// ---------------- merged packing: feat->bf16, w1T, w2T, wpT ----------------
__global__ void pack_all(const float* __restrict__ feat,
                         const float* __restrict__ W1, const float* __restrict__ Wt1,
                         const float* __restrict__ W2, const float* __restrict__ Wt2,
                         const float* __restrict__ Wp,
                         u16* __restrict__ featb, u16* __restrict__ w1T,
                         u16* __restrict__ w2T, u16* __restrict__ wpT, int N) {
  const int CVT = N * 128 / 256;
  int bid = blockIdx.x, t = threadIdx.x;
  if (bid < CVT) {
    int i = bid * 256 + t;
    float4 v = ((const float4*)feat)[i];
    ((u32*)featb)[2 * i] = (u32)f2b(v.x) | ((u32)f2b(v.y) << 16);
    ((u32*)featb)[2 * i + 1] = (u32)f2b(v.z) | ((u32)f2b(v.w) << 16);
  } else if (bid < CVT + 1024) {
    int idx = (bid - CVT) * 256 + t;
    int n = idx >> 9, k = idx & 511;
    float v = (n < 256) ? W1[(size_t)k * 256 + n] : Wt1[(size_t)k * 256 + (n - 256)];
    w1T[idx] = f2b(v);
  } else if (bid < CVT + 2048) {
    int idx = (bid - CVT - 1024) * 256 + t;
    int n = idx >> 9, k = idx & 511;
    float v = 0.f;
    if (n < 256) { if (k < 256) v = W2[(size_t)k * 256 + n]; }
    else { if (k >= 256) v = Wt2[(size_t)(k - 256) * 256 + (n - 256)]; }
    w2T[idx] = f2b(v);
  } else {
    int idx = (bid - CVT - 2048) * 256 + t;
    int n = idx >> 8, k = idx & 255;
    wpT[idx] = f2b(Wp[(size_t)k * 256 + n]);
  }
}

// ---------------- bf16 MFMA GEMM, gload_lds + swizzle + dbuf: C = A @ BT^T ----------------
template <int MODE>  // 0: bf16 out; 1: f32 out
__global__ __launch_bounds__(256, 2) void gemm_bf16(const u16* __restrict__ A,
                                                    const u16* __restrict__ BT,
                                                    void* __restrict__ outp,
                                                    int M, int Nn, int K) {
  __shared__ u16 As[2][128 * 64];
  __shared__ u16 Bs[2][128 * 64];
  const int t = threadIdx.x;
  const int lane = t & 63, wave = t >> 6;
  const int wm = wave >> 1, wn = wave & 1;
  const size_t m0 = (size_t)blockIdx.x * 128, n0 = (size_t)blockIdx.y * 128;
  const int r16 = lane & 15, kg = lane >> 4;
  const int NKT = K >> 6;

  f32x4 acc[4][4];
#pragma unroll
  for (int i = 0; i < 4; ++i)
#pragma unroll
    for (int j = 0; j < 4; ++j) acc[i][j] = (f32x4){0.f, 0.f, 0.f, 0.f};

#pragma unroll
  for (int i = 0; i < 4; ++i) {
    int chunk = (i * 4 + wave) * 64 + lane;
    int row = chunk >> 3, lc = (chunk & 7) ^ (row & 7);
    gload_lds16(A + (m0 + row) * (size_t)K + lc * 8, &As[0][chunk * 8]);
    gload_lds16(BT + (n0 + row) * (size_t)K + lc * 8, &Bs[0][chunk * 8]);
  }

  for (int kt = 0; kt < NKT; ++kt) {
    asm volatile("s_waitcnt vmcnt(0)" ::: "memory");
    __syncthreads();
    if (kt + 1 < NKT) {
      int b = (kt + 1) & 1;
#pragma unroll
      for (int i = 0; i < 4; ++i) {
        int chunk = (i * 4 + wave) * 64 + lane;
        int row = chunk >> 3, lc = (chunk & 7) ^ (row & 7);
        gload_lds16(A + (m0 + row) * (size_t)K + (kt + 1) * 64 + lc * 8, &As[b][chunk * 8]);
        gload_lds16(BT + (n0 + row) * (size_t)K + (kt + 1) * 64 + lc * 8, &Bs[b][chunk * 8]);
      }
    }
    const u16* Ab = &As[kt & 1][0];
    const u16* Bb = &Bs[kt & 1][0];
#pragma unroll
    for (int k0 = 0; k0 < 2; ++k0) {
      const int swz = ((k0 * 4 + kg) ^ (r16 & 7)) << 3;
      bf16x8 af[4], bfv[4];
#pragma unroll
      for (int mi = 0; mi < 4; ++mi)
        af[mi] = *(const bf16x8*)&Ab[(wm * 64 + mi * 16 + r16) * 64 + swz];
#pragma unroll
      for (int ni = 0; ni < 4; ++ni)
        bfv[ni] = *(const bf16x8*)&Bb[(wn * 64 + ni * 16 + r16) * 64 + swz];
#pragma unroll
      for (int mi = 0; mi < 4; ++mi)
#pragma unroll
        for (int ni = 0; ni < 4; ++ni)
          acc[mi][ni] = __builtin_amdgcn_mfma_f32_16x16x32_bf16(af[mi], bfv[ni], acc[mi][ni], 0, 0, 0);
    }
  }

#pragma unroll
  for (int mi = 0; mi < 4; ++mi)
#pragma unroll
    for (int rr = 0; rr < 4; ++rr) {
      size_t row = m0 + wm * 64 + mi * 16 + kg * 4 + rr;
#pragma unroll
      for (int ni = 0; ni < 4; ++ni) {
        size_t col = n0 + wn * 64 + ni * 16 + r16;
        if (MODE == 0)
          ((u16*)outp)[row * Nn + col] = f2b(acc[mi][ni][rr]);
        else
          ((float*)outp)[row * Nn + col] = acc[mi][ni][rr];
      }
    }
}

// ---------------- negsim: A-in-regs strip, gload_lds+swizzle dbuf B ----------------
__global__ __launch_bounds__(256, 2) void negsim_strip(const u16* __restrict__ zb,
                                                       float* __restrict__ partial,
                                                       int M, int NJB) {
  int bid = blockIdx.x;
  int bi = 0, cum = 0;
  for (;;) {
    int nch = (NJB - bi + 3) >> 2;
    if (bid < cum + nch) break;
    cum += nch;
    ++bi;
  }
  const int jc = bid - cum;
  const int bj0 = bi + jc * 4;
  const int ntiles = min(4, NJB - bj0);

  __shared__ u16 Bs[2][128 * 64];
  __shared__ float red[512];
  const int t = threadIdx.x;
  const int lane = t & 63, wave = t >> 6;
  const int wm = wave >> 1, wn = wave & 1;
  const int r16 = lane & 15, kg = lane >> 4;
  const size_t m0 = (size_t)bi * 128;

  // A fragments for full K=256 in registers
  bf16x8 af[4][8];
#pragma unroll
  for (int mi = 0; mi < 4; ++mi) {
    const u16* arow = zb + (m0 + wm * 64 + mi * 16 + r16) * (size_t)HID + kg * 8;
#pragma unroll
    for (int k = 0; k < 8; ++k) af[mi][k] = *(const bf16x8*)(arow + k * 32);
  }

  float rs[4][4];
#pragma unroll
  for (int mi = 0; mi < 4; ++mi)
#pragma unroll
    for (int rr = 0; rr < 4; ++rr) rs[mi][rr] = 0.f;

  for (int tt = 0; tt < ntiles; ++tt) {
    const int bj = bj0 + tt;
    const size_t n0 = (size_t)bj * 128;
    f32x4 acc[4][4];
#pragma unroll
    for (int i = 0; i < 4; ++i)
#pragma unroll
      for (int j = 0; j < 4; ++j) acc[i][j] = (f32x4){0.f, 0.f, 0.f, 0.f};

#pragma unroll
    for (int i = 0; i < 4; ++i) {
      int chunk = (i * 4 + wave) * 64 + lane;
      int row = chunk >> 3, lc = (chunk & 7) ^ (row & 7);
      gload_lds16(zb + (n0 + row) * (size_t)HID + lc * 8, &Bs[0][chunk * 8]);
    }
#pragma unroll
    for (int kt = 0; kt < 4; ++kt) {
      asm volatile("s_waitcnt vmcnt(0)" ::: "memory");
      __syncthreads();
      if (kt < 3) {
        int b = (kt + 1) & 1;
#pragma unroll
        for (int i = 0; i < 4; ++i) {
          int chunk = (i * 4 + wave) * 64 + lane;
          int row = chunk >> 3, lc = (chunk & 7) ^ (row & 7);
          gload_lds16(zb + (n0 + row) * (size_t)HID + (kt + 1) * 64 + lc * 8,
                      &Bs[b][chunk * 8]);
        }
      }
      const u16* Bb = &Bs[kt & 1][0];
#pragma unroll
      for (int k0 = 0; k0 < 2; ++k0) {
        const int swz = ((k0 * 4 + kg) ^ (r16 & 7)) << 3;
        bf16x8 bfv[4];
#pragma unroll
        for (int ni = 0; ni < 4; ++ni)
          bfv[ni] = *(const bf16x8*)&Bb[(wn * 64 + ni * 16 + r16) * 64 + swz];
#pragma unroll
        for (int mi = 0; mi < 4; ++mi)
#pragma unroll
          for (int ni = 0; ni < 4; ++ni)
            acc[mi][ni] = __builtin_amdgcn_mfma_f32_16x16x32_bf16(af[mi][kt * 2 + k0], bfv[ni],
                                                                  acc[mi][ni], 0, 0, 0);
      }
    }

    // exp in place
#pragma unroll
    for (int mi = 0; mi < 4; ++mi)
#pragma unroll
      for (int ni = 0; ni < 4; ++ni)
#pragma unroll
        for (int rr = 0; rr < 4; ++rr)
          acc[mi][ni][rr] = __expf(acc[mi][ni][rr] * TEMP_INV);

    // rowsums accumulate in-register
#pragma unroll
    for (int mi = 0; mi < 4; ++mi)
#pragma unroll
      for (int rr = 0; rr < 4; ++rr)
        rs[mi][rr] += acc[mi][0][rr] + acc[mi][1][rr] + acc[mi][2][rr] + acc[mi][3][rr];

    // colsums for off-diagonal tiles
    if (bj != bi) {
#pragma unroll
      for (int ni = 0; ni < 4; ++ni) {
        float c = 0.f;
#pragma unroll
        for (int mi = 0; mi < 4; ++mi)
#pragma unroll
          for (int rr = 0; rr < 4; ++rr) c += acc[mi][ni][rr];
        c += __shfl_xor(c, 16, 64);
        c += __shfl_xor(c, 32, 64);
        if (kg == 0) red[wm * 256 + wn * 64 + ni * 16 + r16] = c;
      }
      __syncthreads();
      if (t < 128) partial[(size_t)bi * M + n0 + t] = red[t] + red[256 + t];
    }
  }

  // rowsum epilogue
  __syncthreads();
#pragma unroll
  for (int mi = 0; mi < 4; ++mi)
#pragma unroll
    for (int rr = 0; rr < 4; ++rr) {
      float s = rs[mi][rr];
      s += __shfl_xor(s, 1, 64);
      s += __shfl_xor(s, 2, 64);
      s += __shfl_xor(s, 4, 64);
      s += __shfl_xor(s, 8, 64);
      if (r16 == 0) red[wn * 128 + wm * 64 + mi * 16 + kg * 4 + rr] = s;
    }
  __syncthreads();
  if (t < 128) partial[(size_t)(NJB + jc) * M + m0 + t] = red[t] + red[128 + t];
}

// ---------------- CSR gather-aggregate: wave-per-edge, uint4 gathers ----------------
template <bool LAYER2>
__global__ __launch_bounds__(256) void agg_csr(const u16* __restrict__ xw,
                                               const int* __restrict__ csr_src,
                                               const int* __restrict__ offs,
                                               const float* __restrict__ src_norm,
                                               const float* __restrict__ dst_norm,
                                               const float* __restrict__ bias_v,
                                               const float* __restrict__ bias_u,
                                               u16* __restrict__ out_b512,
                                               float* __restrict__ out_f,
                                               u16* __restrict__ out_vb) {
  __shared__ float comb[4][512];
  const int n = blockIdx.x, t = threadIdx.x;
  const int wave = t >> 6, lane = t & 63;
  const int beg = offs[n], end = offs[n + 1];
  float a[8] = {0.f, 0.f, 0.f, 0.f, 0.f, 0.f, 0.f, 0.f};
  for (int i = beg + wave; i < end; i += 4) {
    int s = csr_src[i];
    float w = src_norm[s];
    uint4 p = *(const uint4*)(xw + (size_t)s * 512 + lane * 8);
    a[0] += w * u2f(p.x << 16); a[1] += w * u2f(p.x & 0xFFFF0000u);
    a[2] += w * u2f(p.y << 16); a[3] += w * u2f(p.y & 0xFFFF0000u);
    a[4] += w * u2f(p.z << 16); a[5] += w * u2f(p.z & 0xFFFF0000u);
    a[6] += w * u2f(p.w << 16); a[7] += w * u2f(p.w & 0xFFFF0000u);
  }
  *(float4*)&comb[wave][lane * 8] = make_float4(a[0], a[1], a[2], a[3]);
  *(float4*)&comb[wave][lane * 8 + 4] = make_float4(a[4], a[5], a[6], a[7]);
  __syncthreads();
  int c = 2 * t;
  float v0 = comb[0][c] + comb[1][c] + comb[2][c] + comb[3][c];
  float v1 = comb[0][c + 1] + comb[1][c + 1] + comb[2][c + 1] + comb[3][c + 1];
  float dn = dst_norm[n];
  int cb = c & 255;
  const float* bb = (t < 128) ? bias_v : bias_u;
  v0 = dn * v0 + bb[cb];
  v1 = dn * v1 + bb[cb + 1];
  if (!LAYER2) {
    v0 = fmaxf(v0, 0.f);
    v1 = fmaxf(v1, 0.f);
    ((u32*)out_b512)[(size_t)n * 256 + t] = (u32)f2b(v0) | ((u32)f2b(v1) << 16);
  } else {
    *(float2*)(out_f + (size_t)n * 512 + c) = make_float2(v0, v1);
    if (t < 128)
      ((u32*)out_vb)[(size_t)n * 128 + t] = (u32)f2b(v0) | ((u32)f2b(v1) << 16);
  }
}

// ---------------- merged l2norm for z and un ----------------
__global__ __launch_bounds__(256) void l2norm_zu(const float* __restrict__ vu,
                                                 u16* __restrict__ zb, u16* __restrict__ unb,
                                                 int N) {
  int b = blockIdx.x;
  int isu = b >= N;
  int n = isu ? b - N : b;
  int c = threadIdx.x;
  const float* in = vu + (size_t)n * 512 + (isu ? 256 : 0);
  u16* out = (isu ? unb : zb) + (size_t)n * HID;
  float v = in[c];
  float s = v * v;
#pragma unroll
  for (int m = 1; m < 64; m <<= 1) s += __shfl_xor(s, m, 64);
  __shared__ float red[4];
  if ((c & 63) == 0) red[c >> 6] = s;
  __syncthreads();
  float tot = red[0] + red[1] + red[2] + red[3];
  out[c] = f2b(v / fmaxf(sqrtf(tot), 1e-12f));
}

__global__ __launch_bounds__(256) void l2norm_b(const float* __restrict__ in, int ld,
                                                const float* __restrict__ bias,
                                                u16* __restrict__ out) {
  int n = blockIdx.x, c = threadIdx.x;
  float v = in[(size_t)n * ld + c] + (bias ? bias[c] : 0.f);
  float s = v * v;
#pragma unroll
  for (int m = 1; m < 64; m <<= 1) s += __shfl_xor(s, m, 64);
  __shared__ float red[4];
  if ((c & 63) == 0) red[c >> 6] = s;
  __syncthreads();
  float tot = red[0] + red[1] + red[2] + red[3];
  out[(size_t)n * HID + c] = f2b(v / fmaxf(sqrtf(tot), 1e-12f));
}

// ---------------- neg_sim = sum over partial slots ----------------
__global__ void negsim_reduce(const float* __restrict__ partial, float* __restrict__ neg_sim,
                              int N, int nj) {
  int n = blockIdx.x * 256 + threadIdx.x;
  if (n < N) {
    float s = 0.f;
    for (int j = 0; j < nj; ++j) s += partial[(size_t)j * N + n];
    neg_sim[n] = s;
  }
}

// ---------------- CSR edge scoring: 32 lanes/edge (256 u16 row exactly) ----------------
__global__ __launch_bounds__(256) void edge_csr(const u16* __restrict__ un,
                                                const u16* __restrict__ q,
                                                const int* __restrict__ csr_src,
                                                const int* __restrict__ offs,
                                                const float* __restrict__ neg_sim,
                                                float* __restrict__ score, int N) {
  __shared__ float cpos[8], cneg[8];
  const int n = blockIdx.x, t = threadIdx.x;
  const int hw = t >> 5, lane = t & 31;  // 8 half-waves x 32 lanes
  const int beg = offs[n], end = offs[n + 1];
  const int deg = end - beg;
  // 32 lanes x 8 u16 = 256 u16 = one full row
  uint4 qv = *(const uint4*)(q + (size_t)n * HID + lane * 8);
  const float ns = neg_sim[n];
  float poss = 0.f, negs = 0.f;
  for (int i = beg + hw; i < end; i += 8) {
    int s = csr_src[i];
    uint4 uv = *(const uint4*)(un + (size_t)s * HID + lane * 8);
    float dot = u2f(uv.x << 16) * u2f(qv.x << 16) + u2f(uv.x & 0xFFFF0000u) * u2f(qv.x & 0xFFFF0000u) +
                u2f(uv.y << 16) * u2f(qv.y << 16) + u2f(uv.y & 0xFFFF0000u) * u2f(qv.y & 0xFFFF0000u) +
                u2f(uv.z << 16) * u2f(qv.z << 16) + u2f(uv.z & 0xFFFF0000u) * u2f(qv.z & 0xFFFF0000u) +
                u2f(uv.w << 16) * u2f(qv.w << 16) + u2f(uv.w & 0xFFFF0000u) * u2f(qv.w & 0xFFFF0000u);
    // reduce within the 32-lane half-wave (xor masks 1..16 stay inside the half)
#pragma unroll
    for (int m = 1; m < 32; m <<= 1) dot += __shfl_xor(dot, m, 64);
    float sim = dot * TEMP_INV;
    poss += sim;
    negs += __logf(ns + __expf(sim));
  }
  if (lane == 0) { cpos[hw] = poss; cneg[hw] = negs; }
  __syncthreads();
  if (t == 0) {
    float p = 0.f, g = 0.f;
#pragma unroll
    for (int i = 0; i < 8; ++i) { p += cpos[i]; g += cneg[i]; }
    score[n] = deg > 0 ? (g - p) / (float)deg : 0.f;
  }
}

// ---------------- final mean ----------------
__global__ __launch_bounds__(256) void finalize2(const float* __restrict__ score,
                                                 float* __restrict__ out, int N) {
  float acc = 0.f;
  for (int n = threadIdx.x; n < N; n += 256) acc += score[n];
#pragma unroll
  for (int m = 1; m < 64; m <<= 1) acc += __shfl_xor(acc, m, 64);
  __shared__ float red[4];
  if ((threadIdx.x & 63) == 0) red[threadIdx.x >> 6] = acc;
  __syncthreads();
  if (threadIdx.x == 0) out[0] = (red[0] + red[1] + red[2] + red[3]) / (float)N;
}

extern "C" void kernel_launch(void* const* d_in, const int* in_sizes, int n_in,
                              void* d_out, int out_size, void* d_ws, size_t ws_size,
                              hipStream_t stream) {
  const float* feat = (const float*)d_in[0];
  const int* src = (const int*)d_in[1];
  const int* dst = (const int*)d_in[2];
  const float* W1 = (const float*)d_in[3];
  const float* b1 = (const float*)d_in[4];
  const float* W2 = (const float*)d_in[5];
  const float* b2 = (const float*)d_in[6];
  const float* Wt1 = (const float*)d_in[7];
  const float* bt1 = (const float*)d_in[8];
  const float* Wt2 = (const float*)d_in[9];
  const float* bt2 = (const float*)d_in[10];
  const float* Wp = (const float*)d_in[11];
  const float* bp = (const float*)d_in[12];

  const int N = in_sizes[0] / 512;  // 8192
  const int E = in_sizes[1];        // 262144
  const int NJB = N / 128;          // 64
  const int NSLOT = NJB + 16;

  int nstrip = 0;
  for (int bi = 0; bi < NJB; ++bi) nstrip += (NJB - bi + 3) >> 2;

  char* w = (char*)d_ws;
  size_t off = 0;
  auto alloc = [&](size_t bytes) -> void* {
    void* p = w + off;
    off = (off + bytes + 255) & ~(size_t)255;
    return p;
  };

  float* out_deg = (float*)alloc((size_t)N * 4);
  float* in_deg = (float*)alloc((size_t)N * 4);
  float* src_nrm = (float*)alloc((size_t)N * 4);
  float* dst_nrm = (float*)alloc((size_t)N * 4);
  float* neg_sim = (float*)alloc((size_t)N * 4);
  float* score = (float*)alloc((size_t)N * 4);
  int* offs = (int*)alloc((size_t)(N + 1) * 4);
  int* cursor = (int*)alloc((size_t)N * 4);
  int* csr_src = (int*)alloc((size_t)E * 4);
  u16* w1T = (u16*)alloc(512 * 512 * 2);
  u16* w2T = (u16*)alloc(512 * 512 * 2);
  u16* wpT = (u16*)alloc(256 * 256 * 2);
  u16* featb = (u16*)alloc((size_t)N * 512 * 2);  // reused later: q_pre (f32 N*256)
  u16* XWb = (u16*)alloc((size_t)N * 512 * 2);    // later: zb | unb
  u16* hb = (u16*)alloc((size_t)N * 512 * 2);     // later: vb | qb
  float* vu = (float*)alloc((size_t)N * 512 * 4);
  float* partial = (float*)alloc((size_t)NSLOT * N * 4);

  float* q_pre = (float*)featb;
  u16* zb = XWb;
  u16* unb = XWb + (size_t)N * 256;
  u16* vb = hb;
  u16* qb = hb + (size_t)N * 256;

  dim3 b256(256);

  // degrees, norms, CSR
  hipMemsetAsync(out_deg, 0, 2 * (size_t)N * 4, stream);
  deg_count_kernel<<<(E + 255) / 256, b256, 0, stream>>>(src, dst, out_deg, in_deg, E);
  scan_fused<<<1, b256, 0, stream>>>(in_deg, out_deg, offs, cursor, src_nrm, dst_nrm, N);
  csr_fill<<<(E + 255) / 256, b256, 0, stream>>>(src, dst, cursor, csr_src, E);

  // pack inputs/weights to bf16
  pack_all<<<N * 128 / 256 + 2048 + 256, b256, 0, stream>>>(feat, W1, Wt1, W2, Wt2, Wp,
                                                            featb, w1T, w2T, wpT, N);

  // layer 1 (online+target fused)
  gemm_bf16<0><<<dim3(N / 128, 4), b256, 0, stream>>>(featb, w1T, XWb, N, 512, 512);
  agg_csr<false><<<N, b256, 0, stream>>>(XWb, csr_src, offs, src_nrm, dst_nrm, b1, bt1,
                                         hb, nullptr, nullptr);

  // layer 2
  gemm_bf16<0><<<dim3(N / 128, 4), b256, 0, stream>>>(hb, w2T, XWb, N, 512, 512);
  agg_csr<true><<<N, b256, 0, stream>>>(XWb, csr_src, offs, src_nrm, dst_nrm, b2, bt2,
                                        nullptr, vu, vb);

  // z, un, projector q
  l2norm_zu<<<2 * N, b256, 0, stream>>>(vu, zb, unb, N);
  gemm_bf16<1><<<dim3(N / 128, 2), b256, 0, stream>>>(vb, wpT, q_pre, N, 256, 256);
  l2norm_b<<<N, b256, 0, stream>>>(q_pre, 256, bp, qb);

  // neg_sim: strip kernel over upper triangle
  hipMemsetAsync(partial, 0, (size_t)NSLOT * N * 4, stream);
  negsim_strip<<<nstrip, b256, 0, stream>>>(zb, partial, N, NJB);
  negsim_reduce<<<(N + 255) / 256, b256, 0, stream>>>(partial, neg_sim, N, NSLOT);

  // edge scores (CSR, no atomics) + final mean
  edge_csr<<<N, b256, 0, stream>>>(unb, qb, csr_src, offs, neg_sim, score, N);
  finalize2<<<1, b256, 0, stream>>>(score, (float*)d_out, N);
}